// Round 6
// baseline (168.836 us; speedup 1.0000x reference)
//
#include <hip/hip_runtime.h>
#include <math.h>

#define S_LEN  4096
#define EDIM   64
#define CK     64
#define KSPLIT 4
#define KRANGE (S_LEN / KSPLIT)   // 1024
#define NCH    (KRANGE / CK)      // 16
#define QROWS  64

#define SLOPE_L_ (-0.5f)
#define SLOPE_R_ (-0.70710678118654752440f)

using f16x8 = __attribute__((ext_vector_type(8))) _Float16;
using f32x4 = __attribute__((ext_vector_type(4))) float;
typedef f16x8 f16x8a __attribute__((may_alias));
typedef f32x4 f32x4a __attribute__((may_alias));

// ---------------------------------------------------------------------------
// kernel 1: partial softmax denominators per (q-row, k-slice), no max needed
// (scores bounded: diag >= 0, max score ~15 -> exp fits fp32 comfortably)
// ---------------------------------------------------------------------------
__global__ __launch_bounds__(256, 6)
void den_kernel(const float* __restrict__ Qg, const float* __restrict__ Kg,
                float* __restrict__ wsDen)
{
    __shared__ __align__(16) unsigned char smem[2 * 8192];

    const int tid  = threadIdx.x;
    const int lane = tid & 63;
    const int w    = tid >> 6;      // wave 0..3  -> q-tile
    const int g    = lane >> 4;
    const int c16  = lane & 15;

    // XCD-group swizzle: all 64 q-blocks of one (b,ksl) group land on the
    // same XCD (round-robin pid->XCD, group id in the low 4 bits)
    const int bid  = blockIdx.x;
    const int gidx = bid & 15;          // (b,ksl) group, 16 total for B=4
    const int qb   = bid >> 4;          // 0..63
    const int ksl  = gidx & 3;
    const int b    = gidx >> 2;
    const int q0   = qb * QROWS;
    const int k0   = ksl * KRANGE;

    const float* Qb = Qg + (size_t)b * S_LEN * EDIM;
    const float* Kb = Kg + (size_t)b * S_LEN * EDIM;

    const int srr  = tid >> 2;      // 0..63 : key row within chunk
    const int sseg = tid & 3;       // 16-float segment

    f16x8 qf0, qf1;
    {
        const int row = q0 + w * 16 + c16;
        const float* qp = Qb + (size_t)row * EDIM + g * 8;
        float4 a0 = *(const float4*)(qp + 0);
        float4 a1 = *(const float4*)(qp + 4);
        float4 a2 = *(const float4*)(qp + 32);
        float4 a3 = *(const float4*)(qp + 36);
        const float sc = 0.125f;
        qf0[0]=(_Float16)(a0.x*sc); qf0[1]=(_Float16)(a0.y*sc); qf0[2]=(_Float16)(a0.z*sc); qf0[3]=(_Float16)(a0.w*sc);
        qf0[4]=(_Float16)(a1.x*sc); qf0[5]=(_Float16)(a1.y*sc); qf0[6]=(_Float16)(a1.z*sc); qf0[7]=(_Float16)(a1.w*sc);
        qf1[0]=(_Float16)(a2.x*sc); qf1[1]=(_Float16)(a2.y*sc); qf1[2]=(_Float16)(a2.z*sc); qf1[3]=(_Float16)(a2.w*sc);
        qf1[4]=(_Float16)(a3.x*sc); qf1[5]=(_Float16)(a3.y*sc); qf1[6]=(_Float16)(a3.z*sc); qf1[7]=(_Float16)(a3.w*sc);
    }

    int   qi[4];
    float xq[4], yq[4];
    #pragma unroll
    for (int r = 0; r < 4; ++r) {
        qi[r] = q0 + w * 16 + g * 4 + r;
        xq[r] = (float)(qi[r] >> 6);
        yq[r] = (float)(qi[r] & 63);
    }

    auto loadK = [&](int c, float4* ka) {
        const float* p = Kb + (size_t)(k0 + c * CK + srr) * EDIM + sseg * 16;
        ka[0] = ((const float4*)p)[0];
        ka[1] = ((const float4*)p)[1];
        ka[2] = ((const float4*)p)[2];
        ka[3] = ((const float4*)p)[3];
    };
    auto stageK = [&](int buf, const float4* ka) {
        f16x8 h0, h1;
        h0[0]=(_Float16)ka[0].x; h0[1]=(_Float16)ka[0].y; h0[2]=(_Float16)ka[0].z; h0[3]=(_Float16)ka[0].w;
        h0[4]=(_Float16)ka[1].x; h0[5]=(_Float16)ka[1].y; h0[6]=(_Float16)ka[1].z; h0[7]=(_Float16)ka[1].w;
        h1[0]=(_Float16)ka[2].x; h1[1]=(_Float16)ka[2].y; h1[2]=(_Float16)ka[2].z; h1[3]=(_Float16)ka[2].w;
        h1[4]=(_Float16)ka[3].x; h1[5]=(_Float16)ka[3].y; h1[6]=(_Float16)ka[3].z; h1[7]=(_Float16)ka[3].w;
        const int xr = srr & 7;
        unsigned char* base = smem + buf * 8192 + srr * 128;
        *(f16x8a*)(base + (((sseg * 2    ) ^ xr) << 4)) = h0;
        *(f16x8a*)(base + (((sseg * 2 + 1) ^ xr) << 4)) = h1;
    };

    float accv[4] = {0.f, 0.f, 0.f, 0.f};
    float4 ka[4];
    loadK(0, ka);
    stageK(0, ka);
    if (NCH > 1) loadK(1, ka);
    __syncthreads();

    for (int c = 0; c < NCH; ++c) {
        const int cur = c & 1;
        if (c + 1 < NCH) stageK(cur ^ 1, ka);
        if (c + 2 < NCH) loadK(c + 2, ka);
        const unsigned char* kbase = smem + cur * 8192;
        #pragma unroll
        for (int st = 0; st < 4; ++st) {
            const int rl = st * 16 + c16;
            const int xr = rl & 7;
            const unsigned char* kb = kbase + rl * 128;
            f16x8 bf0 = *(const f16x8a*)(kb + ((g ^ xr) << 4));
            f16x8 bf1 = *(const f16x8a*)(kb + (((g + 4) ^ xr) << 4));
            f32x4 sc = __builtin_amdgcn_mfma_f32_16x16x32_f16(qf0, bf0, (f32x4){0.f,0.f,0.f,0.f}, 0, 0, 0);
            sc = __builtin_amdgcn_mfma_f32_16x16x32_f16(qf1, bf1, sc, 0, 0, 0);
            const int kg = k0 + c * CK + rl;
            const float xk = (float)(kg >> 6);
            const float yk = (float)(kg & 63);
            #pragma unroll
            for (int r = 0; r < 4; ++r) {
                float dist = fabsf(xq[r] - xk) + fabsf(yq[r] - yk);
                float sl = (kg > qi[r]) ? SLOPE_R_ : SLOPE_L_;
                accv[r] += __expf(fmaf(sl, dist, sc[r]));
            }
        }
        __syncthreads();
    }

    #pragma unroll
    for (int r = 0; r < 4; ++r) {
        float v = accv[r];
        v += __shfl_xor(v, 1, 64);
        v += __shfl_xor(v, 2, 64);
        v += __shfl_xor(v, 4, 64);
        v += __shfl_xor(v, 8, 64);
        if (c16 == 0)
            wsDen[((size_t)(b * S_LEN + qi[r])) * KSPLIT + ksl] = v;
    }
}

// ---------------------------------------------------------------------------
// kernel 2: recompute scores, write normalized weights (vectorized nt stores
// via the LDS A-fragment round-trip), partial PV -> plain stores into wsO
// ---------------------------------------------------------------------------
#define LDS2_K   0
#define LDS2_V   16384
#define LDS2_W   32768
#define LDS2_TOT 37888

__global__ __launch_bounds__(256, 4)
void emha2_kernel(const float* __restrict__ Qg, const float* __restrict__ Kg,
                  const float* __restrict__ Vg, const float* __restrict__ wsDen,
                  float* __restrict__ wsO, size_t sliceStride,
                  float* __restrict__ outW)
{
    __shared__ __align__(16) unsigned char smem[LDS2_TOT];

    const int tid  = threadIdx.x;
    const int lane = tid & 63;
    const int w    = tid >> 6;
    const int g    = lane >> 4;
    const int c16  = lane & 15;

    const int bid  = blockIdx.x;
    const int gidx = bid & 15;
    const int qb   = bid >> 4;
    const int ksl  = gidx & 3;
    const int b    = gidx >> 2;
    const int q0   = qb * QROWS;
    const int k0   = ksl * KRANGE;

    const float* Qb = Qg + (size_t)b * S_LEN * EDIM;
    const float* Kb = Kg + (size_t)b * S_LEN * EDIM;
    const float* Vb = Vg + (size_t)b * S_LEN * EDIM;

    const int srr  = tid >> 2;
    const int sseg = tid & 3;

    f16x8 qf0, qf1;
    {
        const int row = q0 + w * 16 + c16;
        const float* qp = Qb + (size_t)row * EDIM + g * 8;
        float4 a0 = *(const float4*)(qp + 0);
        float4 a1 = *(const float4*)(qp + 4);
        float4 a2 = *(const float4*)(qp + 32);
        float4 a3 = *(const float4*)(qp + 36);
        const float sc = 0.125f;
        qf0[0]=(_Float16)(a0.x*sc); qf0[1]=(_Float16)(a0.y*sc); qf0[2]=(_Float16)(a0.z*sc); qf0[3]=(_Float16)(a0.w*sc);
        qf0[4]=(_Float16)(a1.x*sc); qf0[5]=(_Float16)(a1.y*sc); qf0[6]=(_Float16)(a1.z*sc); qf0[7]=(_Float16)(a1.w*sc);
        qf1[0]=(_Float16)(a2.x*sc); qf1[1]=(_Float16)(a2.y*sc); qf1[2]=(_Float16)(a2.z*sc); qf1[3]=(_Float16)(a2.w*sc);
        qf1[4]=(_Float16)(a3.x*sc); qf1[5]=(_Float16)(a3.y*sc); qf1[6]=(_Float16)(a3.z*sc); qf1[7]=(_Float16)(a3.w*sc);
    }

    int   qi[4];
    float xq[4], yq[4], rden[4];
    #pragma unroll
    for (int r = 0; r < 4; ++r) {
        qi[r] = q0 + w * 16 + g * 4 + r;
        xq[r] = (float)(qi[r] >> 6);
        yq[r] = (float)(qi[r] & 63);
        const float* dp = wsDen + ((size_t)(b * S_LEN + qi[r])) * KSPLIT;
        rden[r] = 1.0f / (dp[0] + dp[1] + dp[2] + dp[3]);
    }

    auto loadK = [&](int c, float4* ka) {
        const float* p = Kb + (size_t)(k0 + c * CK + srr) * EDIM + sseg * 16;
        ka[0] = ((const float4*)p)[0];
        ka[1] = ((const float4*)p)[1];
        ka[2] = ((const float4*)p)[2];
        ka[3] = ((const float4*)p)[3];
    };
    auto loadV = [&](int c, float4* va) {
        const float* p = Vb + (size_t)(k0 + c * CK + srr) * EDIM + sseg * 16;
        va[0] = ((const float4*)p)[0];
        va[1] = ((const float4*)p)[1];
        va[2] = ((const float4*)p)[2];
        va[3] = ((const float4*)p)[3];
    };
    auto stageK = [&](int buf, const float4* ka) {
        f16x8 h0, h1;
        h0[0]=(_Float16)ka[0].x; h0[1]=(_Float16)ka[0].y; h0[2]=(_Float16)ka[0].z; h0[3]=(_Float16)ka[0].w;
        h0[4]=(_Float16)ka[1].x; h0[5]=(_Float16)ka[1].y; h0[6]=(_Float16)ka[1].z; h0[7]=(_Float16)ka[1].w;
        h1[0]=(_Float16)ka[2].x; h1[1]=(_Float16)ka[2].y; h1[2]=(_Float16)ka[2].z; h1[3]=(_Float16)ka[2].w;
        h1[4]=(_Float16)ka[3].x; h1[5]=(_Float16)ka[3].y; h1[6]=(_Float16)ka[3].z; h1[7]=(_Float16)ka[3].w;
        const int xr = srr & 7;
        unsigned char* base = smem + LDS2_K + buf * 8192 + srr * 128;
        *(f16x8a*)(base + (((sseg * 2    ) ^ xr) << 4)) = h0;
        *(f16x8a*)(base + (((sseg * 2 + 1) ^ xr) << 4)) = h1;
    };
    // V^T tile: [64 d][64 k] f16, 16B chunks XOR-swizzled by (d&7)
    auto stageV = [&](int buf, const float4* va) {
        unsigned char* vb = smem + LDS2_V + buf * 8192;
        const int cc = srr >> 3;
        const int rb = (srr & 7) << 1;
        auto put = [&](int m, float x) {
            int d = sseg * 16 + m;
            *(_Float16*)(vb + d * 128 + (((cc ^ (d & 7)) << 4)) + rb) = (_Float16)x;
        };
        put(0,  va[0].x); put(1,  va[0].y); put(2,  va[0].z); put(3,  va[0].w);
        put(4,  va[1].x); put(5,  va[1].y); put(6,  va[1].z); put(7,  va[1].w);
        put(8,  va[2].x); put(9,  va[2].y); put(10, va[2].z); put(11, va[2].w);
        put(12, va[3].x); put(13, va[3].y); put(14, va[3].z); put(15, va[3].w);
    };

    f32x4 oacc[4];
    #pragma unroll
    for (int dt = 0; dt < 4; ++dt) oacc[dt] = (f32x4){0.f,0.f,0.f,0.f};

    // W store row/col base for the vectorized path (per-lane row = c16 of tile)
    float* wbaserow = outW + ((size_t)b * S_LEN + q0 + w * 16 + c16) * S_LEN + k0 + g * 8;

    float4 ka[4], va[4];
    loadK(0, ka); loadV(0, va);
    stageK(0, ka); stageV(0, va);
    if (NCH > 1) { loadK(1, ka); loadV(1, va); }
    __syncthreads();

    for (int c = 0; c < NCH; ++c) {
        const int cur = c & 1;
        if (c + 1 < NCH) { stageK(cur ^ 1, ka); stageV(cur ^ 1, va); }
        if (c + 2 < NCH) { loadK(c + 2, ka); loadV(c + 2, va); }
        const unsigned char* kbase = smem + LDS2_K + cur * 8192;
        const unsigned char* vbase = smem + LDS2_V + cur * 8192;
        unsigned char* wbase = smem + LDS2_W + w * 1280;
        #pragma unroll
        for (int win = 0; win < 2; ++win) {
            #pragma unroll
            for (int ss = 0; ss < 2; ++ss) {
                const int st = win * 2 + ss;
                const int rl = st * 16 + c16;
                const int xr = rl & 7;
                const unsigned char* kb = kbase + rl * 128;
                f16x8 bf0 = *(const f16x8a*)(kb + ((g ^ xr) << 4));
                f16x8 bf1 = *(const f16x8a*)(kb + (((g + 4) ^ xr) << 4));
                f32x4 sc = __builtin_amdgcn_mfma_f32_16x16x32_f16(qf0, bf0, (f32x4){0.f,0.f,0.f,0.f}, 0, 0, 0);
                sc = __builtin_amdgcn_mfma_f32_16x16x32_f16(qf1, bf1, sc, 0, 0, 0);
                const int kg = k0 + c * CK + rl;
                const float xk = (float)(kg >> 6);
                const float yk = (float)(kg & 63);
                #pragma unroll
                for (int r = 0; r < 4; ++r) {
                    float dist = fabsf(xq[r] - xk) + fabsf(yq[r] - yk);
                    float sl = (kg > qi[r]) ? SLOPE_R_ : SLOPE_L_;
                    float wv = __expf(fmaf(sl, dist, sc[r])) * rden[r];
                    *(_Float16*)(wbase + (g * 4 + r) * 80 + ((ss * 16 + c16) << 1)) = (_Float16)wv;
                }
            }
            // D-layout -> A-layout redistribution through per-wave LDS buffer.
            // After readback each lane holds 8 consecutive cols of ONE row ->
            // vectorized nontemporal f32 W store (write-once stream, keep out
            // of L2 so K/V tiles stay resident).
            asm volatile("s_waitcnt lgkmcnt(0)" ::: "memory");
            f16x8 af = *(const f16x8a*)(wbase + c16 * 80 + (g << 4));
            {
                f32x4 w0, w1;
                w0[0] = (float)af[0]; w0[1] = (float)af[1]; w0[2] = (float)af[2]; w0[3] = (float)af[3];
                w1[0] = (float)af[4]; w1[1] = (float)af[5]; w1[2] = (float)af[6]; w1[3] = (float)af[7];
                float* wp = wbaserow + c * CK + win * 32;
                __builtin_nontemporal_store(w0, (f32x4a*)(wp));
                __builtin_nontemporal_store(w1, (f32x4a*)(wp + 4));
            }
            #pragma unroll
            for (int dt = 0; dt < 4; ++dt) {
                const int d = dt * 16 + c16;
                const int cc2 = win * 4 + g;
                f16x8 bv = *(const f16x8a*)(vbase + d * 128 + ((cc2 ^ (d & 7)) << 4));
                oacc[dt] = __builtin_amdgcn_mfma_f32_16x16x32_f16(af, bv, oacc[dt], 0, 0, 0);
            }
        }
        __syncthreads();
    }

    // partial O: plain coalesced stores into this slice's region (deterministic)
    {
        float* op = wsO + (size_t)ksl * sliceStride;
        #pragma unroll
        for (int dt = 0; dt < 4; ++dt)
            #pragma unroll
            for (int r = 0; r < 4; ++r)
                op[((size_t)(b * S_LEN + qi[r])) * EDIM + dt * 16 + c16] = oacc[dt][r];
    }
}

// ---------------------------------------------------------------------------
// kernel 3: sum the KSPLIT partial-O slices -> outO  (~36 MB total traffic)
// ---------------------------------------------------------------------------
__global__ __launch_bounds__(256)
void reduceO_kernel(const float* __restrict__ ws, float* __restrict__ out,
                    int n4, size_t s4)
{
    int i = blockIdx.x * 256 + threadIdx.x;
    if (i >= n4) return;
    const size_t e = (size_t)i * 4;
    f32x4 a = __builtin_nontemporal_load((const f32x4a*)(ws + e));
    f32x4 b = __builtin_nontemporal_load((const f32x4a*)(ws + e + s4 * 4));
    f32x4 c = __builtin_nontemporal_load((const f32x4a*)(ws + e + s4 * 8));
    f32x4 d = __builtin_nontemporal_load((const f32x4a*)(ws + e + s4 * 12));
    f32x4 o = (a + b) + (c + d);
    __builtin_nontemporal_store(o, (f32x4a*)(out + e));
}

extern "C" void kernel_launch(void* const* d_in, const int* in_sizes, int n_in,
                              void* d_out, int out_size, void* d_ws, size_t ws_size,
                              hipStream_t stream) {
    const float* Q = (const float*)d_in[0];
    const float* K = (const float*)d_in[1];
    const float* V = (const float*)d_in[2];
    float* outO = (float*)d_out;
    const int B = in_sizes[0] / (S_LEN * EDIM);
    float* outW = outO + (size_t)B * S_LEN * EDIM;

    const size_t nO      = (size_t)B * S_LEN * EDIM;           // output elements
    const size_t needDen = (size_t)B * S_LEN * KSPLIT * sizeof(float);

    float* wsDen = (float*)d_ws;
    float* wsO   = (float*)((char*)d_ws + needDen);

    dim3 grid(B * 64 * KSPLIT);
    den_kernel<<<grid, dim3(256), 0, stream>>>(Q, K, wsDen);
    emha2_kernel<<<grid, dim3(256), 0, stream>>>(Q, K, V, wsDen, wsO, nO, outW);
    int n4 = (int)(nO / 4);
    reduceO_kernel<<<(n4 + 255) / 256, 256, 0, stream>>>(
        wsO, outO, n4, nO / 4);
}

// Round 7
// 112.023 us; speedup vs baseline: 1.5072x; 1.5072x over previous
//
#include <hip/hip_runtime.h>
#include <math.h>

#define S_LEN  4096
#define EDIM   64
#define CK     64
#define KSPLIT 4
#define KRANGE (S_LEN / KSPLIT)   // 1024
#define NCH    (KRANGE / CK)      // 16
#define QROWS  64

#define SLOPE_L_ (-0.5f)
#define SLOPE_R_ (-0.70710678118654752440f)

using f16x8 = __attribute__((ext_vector_type(8))) _Float16;
using f32x4 = __attribute__((ext_vector_type(4))) float;
typedef f16x8 f16x8a __attribute__((may_alias));
typedef f32x4 f32x4a __attribute__((may_alias));

// ---------------------------------------------------------------------------
// kernel 1: partial softmax denominators per (q-row, k-slice), no max needed
// (scores bounded: diag >= 0, max score ~15 -> exp fits fp32 comfortably)
// ---------------------------------------------------------------------------
__global__ __launch_bounds__(256, 6)
void den_kernel(const float* __restrict__ Qg, const float* __restrict__ Kg,
                float* __restrict__ wsDen)
{
    __shared__ __align__(16) unsigned char smem[2 * 8192];

    const int tid  = threadIdx.x;
    const int lane = tid & 63;
    const int w    = tid >> 6;      // wave 0..3  -> q-tile
    const int g    = lane >> 4;
    const int c16  = lane & 15;

    // XCD-group swizzle: all 64 q-blocks of one (b,ksl) group land on the
    // same XCD (round-robin pid->XCD, group id in the low 4 bits)
    const int bid  = blockIdx.x;
    const int gidx = bid & 15;          // (b,ksl) group, 16 total for B=4
    const int qb   = bid >> 4;          // 0..63
    const int ksl  = gidx & 3;
    const int b    = gidx >> 2;
    const int q0   = qb * QROWS;
    const int k0   = ksl * KRANGE;

    const float* Qb = Qg + (size_t)b * S_LEN * EDIM;
    const float* Kb = Kg + (size_t)b * S_LEN * EDIM;

    const int srr  = tid >> 2;      // 0..63 : key row within chunk
    const int sseg = tid & 3;       // 16-float segment

    f16x8 qf0, qf1;
    {
        const int row = q0 + w * 16 + c16;
        const float* qp = Qb + (size_t)row * EDIM + g * 8;
        float4 a0 = *(const float4*)(qp + 0);
        float4 a1 = *(const float4*)(qp + 4);
        float4 a2 = *(const float4*)(qp + 32);
        float4 a3 = *(const float4*)(qp + 36);
        const float sc = 0.125f;
        qf0[0]=(_Float16)(a0.x*sc); qf0[1]=(_Float16)(a0.y*sc); qf0[2]=(_Float16)(a0.z*sc); qf0[3]=(_Float16)(a0.w*sc);
        qf0[4]=(_Float16)(a1.x*sc); qf0[5]=(_Float16)(a1.y*sc); qf0[6]=(_Float16)(a1.z*sc); qf0[7]=(_Float16)(a1.w*sc);
        qf1[0]=(_Float16)(a2.x*sc); qf1[1]=(_Float16)(a2.y*sc); qf1[2]=(_Float16)(a2.z*sc); qf1[3]=(_Float16)(a2.w*sc);
        qf1[4]=(_Float16)(a3.x*sc); qf1[5]=(_Float16)(a3.y*sc); qf1[6]=(_Float16)(a3.z*sc); qf1[7]=(_Float16)(a3.w*sc);
    }

    int   qi[4];
    float xq[4], yq[4];
    #pragma unroll
    for (int r = 0; r < 4; ++r) {
        qi[r] = q0 + w * 16 + g * 4 + r;
        xq[r] = (float)(qi[r] >> 6);
        yq[r] = (float)(qi[r] & 63);
    }

    auto loadK = [&](int c, float4* ka) {
        const float* p = Kb + (size_t)(k0 + c * CK + srr) * EDIM + sseg * 16;
        ka[0] = ((const float4*)p)[0];
        ka[1] = ((const float4*)p)[1];
        ka[2] = ((const float4*)p)[2];
        ka[3] = ((const float4*)p)[3];
    };
    auto stageK = [&](int buf, const float4* ka) {
        f16x8 h0, h1;
        h0[0]=(_Float16)ka[0].x; h0[1]=(_Float16)ka[0].y; h0[2]=(_Float16)ka[0].z; h0[3]=(_Float16)ka[0].w;
        h0[4]=(_Float16)ka[1].x; h0[5]=(_Float16)ka[1].y; h0[6]=(_Float16)ka[1].z; h0[7]=(_Float16)ka[1].w;
        h1[0]=(_Float16)ka[2].x; h1[1]=(_Float16)ka[2].y; h1[2]=(_Float16)ka[2].z; h1[3]=(_Float16)ka[2].w;
        h1[4]=(_Float16)ka[3].x; h1[5]=(_Float16)ka[3].y; h1[6]=(_Float16)ka[3].z; h1[7]=(_Float16)ka[3].w;
        const int xr = srr & 7;
        unsigned char* base = smem + buf * 8192 + srr * 128;
        *(f16x8a*)(base + (((sseg * 2    ) ^ xr) << 4)) = h0;
        *(f16x8a*)(base + (((sseg * 2 + 1) ^ xr) << 4)) = h1;
    };

    float accv[4] = {0.f, 0.f, 0.f, 0.f};
    float4 ka[4];
    loadK(0, ka);
    stageK(0, ka);
    if (NCH > 1) loadK(1, ka);
    __syncthreads();

    for (int c = 0; c < NCH; ++c) {
        const int cur = c & 1;
        if (c + 1 < NCH) stageK(cur ^ 1, ka);
        if (c + 2 < NCH) loadK(c + 2, ka);
        const unsigned char* kbase = smem + cur * 8192;
        #pragma unroll
        for (int st = 0; st < 4; ++st) {
            const int rl = st * 16 + c16;
            const int xr = rl & 7;
            const unsigned char* kb = kbase + rl * 128;
            f16x8 bf0 = *(const f16x8a*)(kb + ((g ^ xr) << 4));
            f16x8 bf1 = *(const f16x8a*)(kb + (((g + 4) ^ xr) << 4));
            f32x4 sc = __builtin_amdgcn_mfma_f32_16x16x32_f16(qf0, bf0, (f32x4){0.f,0.f,0.f,0.f}, 0, 0, 0);
            sc = __builtin_amdgcn_mfma_f32_16x16x32_f16(qf1, bf1, sc, 0, 0, 0);
            const int kg = k0 + c * CK + rl;
            const float xk = (float)(kg >> 6);
            const float yk = (float)(kg & 63);
            #pragma unroll
            for (int r = 0; r < 4; ++r) {
                float dist = fabsf(xq[r] - xk) + fabsf(yq[r] - yk);
                float sl = (kg > qi[r]) ? SLOPE_R_ : SLOPE_L_;
                accv[r] += __expf(fmaf(sl, dist, sc[r]));
            }
        }
        __syncthreads();
    }

    #pragma unroll
    for (int r = 0; r < 4; ++r) {
        float v = accv[r];
        v += __shfl_xor(v, 1, 64);
        v += __shfl_xor(v, 2, 64);
        v += __shfl_xor(v, 4, 64);
        v += __shfl_xor(v, 8, 64);
        if (c16 == 0)
            wsDen[((size_t)(b * S_LEN + qi[r])) * KSPLIT + ksl] = v;
    }
}

// ---------------------------------------------------------------------------
// kernel 2: recompute scores, write normalized weights (vectorized f32 stores
// via the LDS A-fragment round-trip), partial PV -> plain stores into wsO
// ---------------------------------------------------------------------------
#define LDS2_K   0
#define LDS2_V   16384
#define LDS2_W   32768
#define LDS2_TOT 37888

__global__ __launch_bounds__(256, 4)
void emha2_kernel(const float* __restrict__ Qg, const float* __restrict__ Kg,
                  const float* __restrict__ Vg, const float* __restrict__ wsDen,
                  float* __restrict__ wsO, size_t sliceStride,
                  float* __restrict__ outW)
{
    __shared__ __align__(16) unsigned char smem[LDS2_TOT];

    const int tid  = threadIdx.x;
    const int lane = tid & 63;
    const int w    = tid >> 6;
    const int g    = lane >> 4;
    const int c16  = lane & 15;

    const int bid  = blockIdx.x;
    const int gidx = bid & 15;
    const int qb   = bid >> 4;
    const int ksl  = gidx & 3;
    const int b    = gidx >> 2;
    const int q0   = qb * QROWS;
    const int k0   = ksl * KRANGE;

    const float* Qb = Qg + (size_t)b * S_LEN * EDIM;
    const float* Kb = Kg + (size_t)b * S_LEN * EDIM;
    const float* Vb = Vg + (size_t)b * S_LEN * EDIM;

    const int srr  = tid >> 2;
    const int sseg = tid & 3;

    f16x8 qf0, qf1;
    {
        const int row = q0 + w * 16 + c16;
        const float* qp = Qb + (size_t)row * EDIM + g * 8;
        float4 a0 = *(const float4*)(qp + 0);
        float4 a1 = *(const float4*)(qp + 4);
        float4 a2 = *(const float4*)(qp + 32);
        float4 a3 = *(const float4*)(qp + 36);
        const float sc = 0.125f;
        qf0[0]=(_Float16)(a0.x*sc); qf0[1]=(_Float16)(a0.y*sc); qf0[2]=(_Float16)(a0.z*sc); qf0[3]=(_Float16)(a0.w*sc);
        qf0[4]=(_Float16)(a1.x*sc); qf0[5]=(_Float16)(a1.y*sc); qf0[6]=(_Float16)(a1.z*sc); qf0[7]=(_Float16)(a1.w*sc);
        qf1[0]=(_Float16)(a2.x*sc); qf1[1]=(_Float16)(a2.y*sc); qf1[2]=(_Float16)(a2.z*sc); qf1[3]=(_Float16)(a2.w*sc);
        qf1[4]=(_Float16)(a3.x*sc); qf1[5]=(_Float16)(a3.y*sc); qf1[6]=(_Float16)(a3.z*sc); qf1[7]=(_Float16)(a3.w*sc);
    }

    int   qi[4];
    float xq[4], yq[4], rden[4];
    #pragma unroll
    for (int r = 0; r < 4; ++r) {
        qi[r] = q0 + w * 16 + g * 4 + r;
        xq[r] = (float)(qi[r] >> 6);
        yq[r] = (float)(qi[r] & 63);
        const float* dp = wsDen + ((size_t)(b * S_LEN + qi[r])) * KSPLIT;
        rden[r] = 1.0f / (dp[0] + dp[1] + dp[2] + dp[3]);
    }

    auto loadK = [&](int c, float4* ka) {
        const float* p = Kb + (size_t)(k0 + c * CK + srr) * EDIM + sseg * 16;
        ka[0] = ((const float4*)p)[0];
        ka[1] = ((const float4*)p)[1];
        ka[2] = ((const float4*)p)[2];
        ka[3] = ((const float4*)p)[3];
    };
    auto loadV = [&](int c, float4* va) {
        const float* p = Vb + (size_t)(k0 + c * CK + srr) * EDIM + sseg * 16;
        va[0] = ((const float4*)p)[0];
        va[1] = ((const float4*)p)[1];
        va[2] = ((const float4*)p)[2];
        va[3] = ((const float4*)p)[3];
    };
    auto stageK = [&](int buf, const float4* ka) {
        f16x8 h0, h1;
        h0[0]=(_Float16)ka[0].x; h0[1]=(_Float16)ka[0].y; h0[2]=(_Float16)ka[0].z; h0[3]=(_Float16)ka[0].w;
        h0[4]=(_Float16)ka[1].x; h0[5]=(_Float16)ka[1].y; h0[6]=(_Float16)ka[1].z; h0[7]=(_Float16)ka[1].w;
        h1[0]=(_Float16)ka[2].x; h1[1]=(_Float16)ka[2].y; h1[2]=(_Float16)ka[2].z; h1[3]=(_Float16)ka[2].w;
        h1[4]=(_Float16)ka[3].x; h1[5]=(_Float16)ka[3].y; h1[6]=(_Float16)ka[3].z; h1[7]=(_Float16)ka[3].w;
        const int xr = srr & 7;
        unsigned char* base = smem + LDS2_K + buf * 8192 + srr * 128;
        *(f16x8a*)(base + (((sseg * 2    ) ^ xr) << 4)) = h0;
        *(f16x8a*)(base + (((sseg * 2 + 1) ^ xr) << 4)) = h1;
    };
    // V^T tile: [64 d][64 k] f16, 16B chunks XOR-swizzled by (d&7)
    auto stageV = [&](int buf, const float4* va) {
        unsigned char* vb = smem + LDS2_V + buf * 8192;
        const int cc = srr >> 3;
        const int rb = (srr & 7) << 1;
        auto put = [&](int m, float x) {
            int d = sseg * 16 + m;
            *(_Float16*)(vb + d * 128 + (((cc ^ (d & 7)) << 4)) + rb) = (_Float16)x;
        };
        put(0,  va[0].x); put(1,  va[0].y); put(2,  va[0].z); put(3,  va[0].w);
        put(4,  va[1].x); put(5,  va[1].y); put(6,  va[1].z); put(7,  va[1].w);
        put(8,  va[2].x); put(9,  va[2].y); put(10, va[2].z); put(11, va[2].w);
        put(12, va[3].x); put(13, va[3].y); put(14, va[3].z); put(15, va[3].w);
    };

    f32x4 oacc[4];
    #pragma unroll
    for (int dt = 0; dt < 4; ++dt) oacc[dt] = (f32x4){0.f,0.f,0.f,0.f};

    // W store row/col base for the vectorized path (per-lane row = c16 of tile)
    float* wbaserow = outW + ((size_t)b * S_LEN + q0 + w * 16 + c16) * S_LEN + k0 + g * 8;

    float4 ka[4], va[4];
    loadK(0, ka); loadV(0, va);
    stageK(0, ka); stageV(0, va);
    if (NCH > 1) { loadK(1, ka); loadV(1, va); }
    __syncthreads();

    for (int c = 0; c < NCH; ++c) {
        const int cur = c & 1;
        if (c + 1 < NCH) { stageK(cur ^ 1, ka); stageV(cur ^ 1, va); }
        if (c + 2 < NCH) { loadK(c + 2, ka); loadV(c + 2, va); }
        const unsigned char* kbase = smem + LDS2_K + cur * 8192;
        const unsigned char* vbase = smem + LDS2_V + cur * 8192;
        unsigned char* wbase = smem + LDS2_W + w * 1280;
        #pragma unroll
        for (int win = 0; win < 2; ++win) {
            #pragma unroll
            for (int ss = 0; ss < 2; ++ss) {
                const int st = win * 2 + ss;
                const int rl = st * 16 + c16;
                const int xr = rl & 7;
                const unsigned char* kb = kbase + rl * 128;
                f16x8 bf0 = *(const f16x8a*)(kb + ((g ^ xr) << 4));
                f16x8 bf1 = *(const f16x8a*)(kb + (((g + 4) ^ xr) << 4));
                f32x4 sc = __builtin_amdgcn_mfma_f32_16x16x32_f16(qf0, bf0, (f32x4){0.f,0.f,0.f,0.f}, 0, 0, 0);
                sc = __builtin_amdgcn_mfma_f32_16x16x32_f16(qf1, bf1, sc, 0, 0, 0);
                const int kg = k0 + c * CK + rl;
                const float xk = (float)(kg >> 6);
                const float yk = (float)(kg & 63);
                #pragma unroll
                for (int r = 0; r < 4; ++r) {
                    float dist = fabsf(xq[r] - xk) + fabsf(yq[r] - yk);
                    float sl = (kg > qi[r]) ? SLOPE_R_ : SLOPE_L_;
                    float wv = __expf(fmaf(sl, dist, sc[r])) * rden[r];
                    *(_Float16*)(wbase + (g * 4 + r) * 80 + ((ss * 16 + c16) << 1)) = (_Float16)wv;
                }
            }
            // D-layout -> A-layout redistribution through per-wave LDS buffer.
            // After readback each lane holds 8 consecutive cols of ONE row ->
            // vectorized f32 W store (2x dwordx4, plain — nt stores measured
            // -41 us in round 6, reverted).
            asm volatile("s_waitcnt lgkmcnt(0)" ::: "memory");
            f16x8 af = *(const f16x8a*)(wbase + c16 * 80 + (g << 4));
            {
                f32x4 w0, w1;
                w0[0] = (float)af[0]; w0[1] = (float)af[1]; w0[2] = (float)af[2]; w0[3] = (float)af[3];
                w1[0] = (float)af[4]; w1[1] = (float)af[5]; w1[2] = (float)af[6]; w1[3] = (float)af[7];
                float* wp = wbaserow + c * CK + win * 32;
                *(f32x4a*)(wp)     = w0;
                *(f32x4a*)(wp + 4) = w1;
            }
            #pragma unroll
            for (int dt = 0; dt < 4; ++dt) {
                const int d = dt * 16 + c16;
                const int cc2 = win * 4 + g;
                f16x8 bv = *(const f16x8a*)(vbase + d * 128 + ((cc2 ^ (d & 7)) << 4));
                oacc[dt] = __builtin_amdgcn_mfma_f32_16x16x32_f16(af, bv, oacc[dt], 0, 0, 0);
            }
        }
        __syncthreads();
    }

    // partial O: plain coalesced stores into this slice's region (deterministic)
    {
        float* op = wsO + (size_t)ksl * sliceStride;
        #pragma unroll
        for (int dt = 0; dt < 4; ++dt)
            #pragma unroll
            for (int r = 0; r < 4; ++r)
                op[((size_t)(b * S_LEN + qi[r])) * EDIM + dt * 16 + c16] = oacc[dt][r];
    }
}

// ---------------------------------------------------------------------------
// kernel 3: sum the KSPLIT partial-O slices -> outO  (~36 MB total traffic)
// ---------------------------------------------------------------------------
__global__ __launch_bounds__(256)
void reduceO_kernel(const float* __restrict__ ws, float* __restrict__ out,
                    int n4, size_t s4)
{
    int i = blockIdx.x * 256 + threadIdx.x;
    if (i >= n4) return;
    const size_t e = (size_t)i * 4;
    f32x4 a = *(const f32x4a*)(ws + e);
    f32x4 b = *(const f32x4a*)(ws + e + s4 * 4);
    f32x4 c = *(const f32x4a*)(ws + e + s4 * 8);
    f32x4 d = *(const f32x4a*)(ws + e + s4 * 12);
    f32x4 o = (a + b) + (c + d);
    *(f32x4a*)(out + e) = o;
}

extern "C" void kernel_launch(void* const* d_in, const int* in_sizes, int n_in,
                              void* d_out, int out_size, void* d_ws, size_t ws_size,
                              hipStream_t stream) {
    const float* Q = (const float*)d_in[0];
    const float* K = (const float*)d_in[1];
    const float* V = (const float*)d_in[2];
    float* outO = (float*)d_out;
    const int B = in_sizes[0] / (S_LEN * EDIM);
    float* outW = outO + (size_t)B * S_LEN * EDIM;

    const size_t nO      = (size_t)B * S_LEN * EDIM;           // output elements
    const size_t needDen = (size_t)B * S_LEN * KSPLIT * sizeof(float);

    float* wsDen = (float*)d_ws;
    float* wsO   = (float*)((char*)d_ws + needDen);

    dim3 grid(B * 64 * KSPLIT);
    den_kernel<<<grid, dim3(256), 0, stream>>>(Q, K, wsDen);
    emha2_kernel<<<grid, dim3(256), 0, stream>>>(Q, K, V, wsDen, wsO, nO, outW);
    int n4 = (int)(nO / 4);
    reduceO_kernel<<<(n4 + 255) / 256, 256, 0, stream>>>(
        wsO, outO, n4, nO / 4);
}